// Round 1
// baseline (122.768 us; speedup 1.0000x reference)
//
#include <hip/hip_runtime.h>
#include <hip/hip_bf16.h>
#include <math.h>

// Problem constants
#define BATCH 1024
#define X_DIM 32
#define U_DIM 8
#define PHI 128
#define HID 128

// ---------------------------------------------------------------------------
// Kernel 1: MLP encoder. One block per batch row, 128 threads (one per hidden
// unit). h lives in LDS between layers. Weight reads are coalesced across
// threads (thread j reads W[k*128+j]); total weights ~200KB -> L2 resident.
// ---------------------------------------------------------------------------
__global__ __launch_bounds__(128) void mlp_kernel(
    const float* __restrict__ x,
    const float* __restrict__ W1, const float* __restrict__ b1,
    const float* __restrict__ W2, const float* __restrict__ b2,
    const float* __restrict__ W3, const float* __restrict__ b3,
    const float* __restrict__ W4, const float* __restrict__ b4,
    float* __restrict__ phiv)
{
    const int b = blockIdx.x;
    const int j = threadIdx.x;  // 0..127

    __shared__ float sx[X_DIM];
    __shared__ float h[HID];

    if (j < X_DIM) sx[j] = x[b * X_DIM + j];
    __syncthreads();

    // layer 1: 32 -> 128, tanh
    float acc = b1[j];
#pragma unroll
    for (int k = 0; k < X_DIM; ++k) acc += sx[k] * W1[k * HID + j];
    float hv = tanhf(acc);
    h[j] = hv;
    __syncthreads();

    // layer 2: 128 -> 128, tanh
    acc = b2[j];
#pragma unroll 8
    for (int k = 0; k < HID; ++k) acc += h[k] * W2[k * HID + j];
    hv = tanhf(acc);
    __syncthreads();
    h[j] = hv;
    __syncthreads();

    // layer 3: 128 -> 128, tanh
    acc = b3[j];
#pragma unroll 8
    for (int k = 0; k < HID; ++k) acc += h[k] * W3[k * HID + j];
    hv = tanhf(acc);
    __syncthreads();
    h[j] = hv;
    __syncthreads();

    // layer 4: 128 -> 128, linear
    acc = b4[j];
#pragma unroll 8
    for (int k = 0; k < HID; ++k) acc += h[k] * W4[k * HID + j];
    phiv[b * PHI + j] = acc;
}

// ---------------------------------------------------------------------------
// Kernel 2: bilinear forms over L. One block per (b,u), 256 threads.
//   mu[b,u]  = sum_{p,q} Q[b,u,p] * L[b,u,p,q] * phi[b,q]
//   sf[b,u]  = 1 + sum_{p,q} phi[b,p] * L[b,u,p,q] * phi[b,q]
// L tile (64KB) is streamed with fully coalesced float4 loads:
// thread t takes float4 linear index t + 256*i (i=0..15);
// row p = 8*i + (t>>5), float4-col c = t&31 (fixed per thread).
// ---------------------------------------------------------------------------
__global__ __launch_bounds__(256) void bilinear_kernel(
    const float* __restrict__ Q,
    const float* __restrict__ L,
    const float* __restrict__ phiv,
    const float* __restrict__ logSigEps,
    float* __restrict__ mu_out,   // (B,U,1) flat = 8192
    float* __restrict__ sig_out)  // (B,U,U) flat = 65536
{
    const int bu = blockIdx.x;        // 0..8191
    const int b  = bu >> 3;
    const int u  = bu & 7;
    const int t  = threadIdx.x;       // 0..255

    const float4* __restrict__ L4 = (const float4*)(L + (size_t)bu * PHI * PHI);

    __shared__ float s_phi[PHI];
    __shared__ float s_Q[PHI];
    __shared__ float red[8];
    __shared__ float s_bcast[2];

    if (t < PHI) {
        s_phi[t] = phiv[(size_t)b * PHI + t];
        s_Q[t]   = Q[(size_t)bu * PHI + t];
    }
    __syncthreads();

    const int c  = t & 31;   // float4 column, fixed per thread
    const int r0 = t >> 5;   // 0..7
    const float4 phi4 = ((const float4*)s_phi)[c];

    float acc_mu = 0.0f;
    float acc_sf = 0.0f;
#pragma unroll
    for (int i = 0; i < 16; ++i) {
        const int r = i * 8 + r0;
        const float4 v = L4[i * 256 + t];   // coalesced: consecutive t -> consecutive 16B
        const float s = v.x * phi4.x + v.y * phi4.y + v.z * phi4.z + v.w * phi4.w;
        acc_mu += s * s_Q[r];     // broadcast LDS read (same addr across 32 lanes)
        acc_sf += s * s_phi[r];
    }

    // wave (64-lane) butterfly reduction
    float m = acc_mu, f = acc_sf;
#pragma unroll
    for (int off = 1; off < 64; off <<= 1) {
        m += __shfl_xor(m, off);
        f += __shfl_xor(f, off);
    }
    const int wave = t >> 6;  // 0..3
    if ((t & 63) == 0) {
        red[wave * 2 + 0] = m;
        red[wave * 2 + 1] = f;
    }
    __syncthreads();

    if (t == 0) {
        const float mu = red[0] + red[2] + red[4] + red[6];
        const float sf = 1.0f + red[1] + red[3] + red[5] + red[7];
        s_bcast[0] = mu;
        s_bcast[1] = sf;
    }
    __syncthreads();

    if (t == 0) {
        mu_out[bu] = s_bcast[0];
    }
    // sig row for this (b,u): sig[b,u,v] = (v==u) ? exp(logSigEps[u])*sf : 0
    if (t < U_DIM) {
        const float sf = s_bcast[1];
        const float val = (t == u) ? __expf(logSigEps[u]) * sf : 0.0f;
        sig_out[(size_t)bu * U_DIM + t] = val;
    }
}

extern "C" void kernel_launch(void* const* d_in, const int* in_sizes, int n_in,
                              void* d_out, int out_size, void* d_ws, size_t ws_size,
                              hipStream_t stream)
{
    const float* x         = (const float*)d_in[0];
    const float* Q         = (const float*)d_in[1];
    const float* L         = (const float*)d_in[2];
    const float* W1        = (const float*)d_in[3];
    const float* b1        = (const float*)d_in[4];
    const float* W2        = (const float*)d_in[5];
    const float* b2        = (const float*)d_in[6];
    const float* W3        = (const float*)d_in[7];
    const float* b3        = (const float*)d_in[8];
    const float* W4        = (const float*)d_in[9];
    const float* b4        = (const float*)d_in[10];
    const float* logSigEps = (const float*)d_in[11];

    float* out    = (float*)d_out;
    float* mu_out = out;                    // 8192 elements (B,U,1)
    float* sig_out = out + BATCH * U_DIM;   // 65536 elements (B,U,U)

    float* phiv = (float*)d_ws;             // B*PHI floats = 512KB

    mlp_kernel<<<BATCH, 128, 0, stream>>>(x, W1, b1, W2, b2, W3, b3, W4, b4, phiv);
    bilinear_kernel<<<BATCH * U_DIM, 256, 0, stream>>>(Q, L, phiv, logSigEps,
                                                       mu_out, sig_out);
}

// Round 2
// 97.544 us; speedup vs baseline: 1.2586x; 1.2586x over previous
//
#include <hip/hip_runtime.h>
#include <hip/hip_bf16.h>
#include <math.h>

// Problem constants
#define BATCH 1024
#define X_DIM 32
#define U_DIM 8
#define PHI 128
#define HID 128

typedef float f4 __attribute__((ext_vector_type(4)));

__device__ __forceinline__ float fast_tanh(float x) {
    // tanh(x) = 1 - 2/(exp(2x)+1); exact limits at +-inf, monotone, err ~1e-7 rel
    return 1.0f - 2.0f / (__expf(2.0f * x) + 1.0f);
}

// ---------------------------------------------------------------------------
// Fused kernel: one block per batch row b, 512 threads (8 waves).
// Phase 1: threads 0..127 run the MLP (weights are L2-resident after the
//          first blocks touch them); other waves wait at the barrier.
// Phase 2: wave w streams L[b,u=w] (64KB) with non-temporal float4 loads,
//          accumulates the two bilinear forms, reduces intra-wave only
//          (no barriers, no cross-wave LDS reduce).
//   mu[b,u] = sum_{p,q} Q[b,u,p] L[b,u,p,q] phi[b,q]
//   sf[b,u] = 1 + sum_{p,q} phi[b,p] L[b,u,p,q] phi[b,q]
//   sig[b,u,v] = (v==u) ? exp(logSigEps[u]) * sf : 0
// ---------------------------------------------------------------------------
__global__ __launch_bounds__(512) void fused_kernel(
    const float* __restrict__ x,
    const float* __restrict__ Q,
    const float* __restrict__ L,
    const float* __restrict__ W1, const float* __restrict__ b1,
    const float* __restrict__ W2, const float* __restrict__ b2,
    const float* __restrict__ W3, const float* __restrict__ b3,
    const float* __restrict__ W4, const float* __restrict__ b4,
    const float* __restrict__ logSigEps,
    float* __restrict__ mu_out,   // 8192 = (B,U,1)
    float* __restrict__ sig_out)  // 65536 = (B,U,U)
{
    const int b = blockIdx.x;
    const int t = threadIdx.x;     // 0..511

    __shared__ float sx[X_DIM];
    __shared__ float h[HID];
    __shared__ float s_phi[PHI];
    __shared__ float s_Q[U_DIM * PHI];   // 4KB

    // preload Q (1024 floats) with all 512 threads, and x with the first 32
    {
        const float2* Qg = (const float2*)(Q + (size_t)b * (U_DIM * PHI));
        ((float2*)s_Q)[t] = Qg[t];
    }
    if (t < X_DIM) sx[t] = x[b * X_DIM + t];
    __syncthreads();

    // ---- Phase 1: MLP on threads 0..127 ----
    float acc;
    if (t < HID) {
        acc = b1[t];
#pragma unroll
        for (int k = 0; k < X_DIM; ++k) acc += sx[k] * W1[k * HID + t];
        h[t] = fast_tanh(acc);
    }
    __syncthreads();
    if (t < HID) {
        acc = b2[t];
#pragma unroll 8
        for (int k = 0; k < HID; ++k) acc += h[k] * W2[k * HID + t];
        acc = fast_tanh(acc);
    }
    __syncthreads();
    if (t < HID) h[t] = acc;
    __syncthreads();
    if (t < HID) {
        acc = b3[t];
#pragma unroll 8
        for (int k = 0; k < HID; ++k) acc += h[k] * W3[k * HID + t];
        acc = fast_tanh(acc);
    }
    __syncthreads();
    if (t < HID) h[t] = acc;
    __syncthreads();
    if (t < HID) {
        acc = b4[t];
#pragma unroll 8
        for (int k = 0; k < HID; ++k) acc += h[k] * W4[k * HID + t];
        s_phi[t] = acc;
    }
    __syncthreads();

    // ---- Phase 2: per-wave bilinear stream ----
    const int u = t >> 6;          // wave id = u, 0..7
    const int l = t & 63;          // lane
    const int c = l & 31;          // float4 column (fixed per lane)
    const int h0 = l >> 5;         // 0 or 1

    const f4* __restrict__ L4 = (const f4*)(L + ((size_t)(b * U_DIM + u)) * (PHI * PHI));
    const f4 phi4 = ((const f4*)s_phi)[c];
    const float* __restrict__ Qu = s_Q + u * PHI;

    float accm = 0.0f, accf = 0.0f;
#pragma unroll 8
    for (int i = 0; i < 64; ++i) {
        const f4 v = __builtin_nontemporal_load(L4 + (i * 64 + l));  // coalesced 1KB/wave-inst
        const int r = 2 * i + h0;
        const float s = v.x * phi4.x + v.y * phi4.y + v.z * phi4.z + v.w * phi4.w;
        accm += s * Qu[r];
        accf += s * s_phi[r];
    }

    // intra-wave butterfly reduction (64 lanes)
#pragma unroll
    for (int off = 1; off < 64; off <<= 1) {
        accm += __shfl_xor(accm, off);
        accf += __shfl_xor(accf, off);
    }

    const int bu = b * U_DIM + u;
    if (l == 0) mu_out[bu] = accm;
    if (l < U_DIM) {
        const float sf = 1.0f + accf;
        sig_out[(size_t)bu * U_DIM + l] = (l == u) ? __expf(logSigEps[u]) * sf : 0.0f;
    }
}

extern "C" void kernel_launch(void* const* d_in, const int* in_sizes, int n_in,
                              void* d_out, int out_size, void* d_ws, size_t ws_size,
                              hipStream_t stream)
{
    const float* x         = (const float*)d_in[0];
    const float* Q         = (const float*)d_in[1];
    const float* L         = (const float*)d_in[2];
    const float* W1        = (const float*)d_in[3];
    const float* b1        = (const float*)d_in[4];
    const float* W2        = (const float*)d_in[5];
    const float* b2        = (const float*)d_in[6];
    const float* W3        = (const float*)d_in[7];
    const float* b3        = (const float*)d_in[8];
    const float* W4        = (const float*)d_in[9];
    const float* b4        = (const float*)d_in[10];
    const float* logSigEps = (const float*)d_in[11];

    float* out     = (float*)d_out;
    float* mu_out  = out;                   // 8192
    float* sig_out = out + BATCH * U_DIM;   // 65536

    fused_kernel<<<BATCH, 512, 0, stream>>>(x, Q, L,
                                            W1, b1, W2, b2, W3, b3, W4, b4,
                                            logSigEps, mu_out, sig_out);
}

// Round 3
// 77.579 us; speedup vs baseline: 1.5825x; 1.2574x over previous
//
#include <hip/hip_runtime.h>
#include <hip/hip_bf16.h>
#include <math.h>

// Problem constants
#define BATCH 1024
#define X_DIM 32
#define U_DIM 8
#define PHI 128
#define HID 128

// number of float4 tasks in the padded lower triangle:
// sum_r ceil((r+1)/4) = 2112 = 33 * 64  (exactly 33 iters per 64-lane wave)
#define NTASK 2112

typedef float f4 __attribute__((ext_vector_type(4)));

__device__ __forceinline__ float fast_tanh(float x) {
    return 1.0f - 2.0f / (__expf(2.0f * x) + 1.0f);
}

// ---------------------------------------------------------------------------
// Fused kernel, symmetry-aware: one block per batch row b, 512 threads.
// L[b,u] is exactly symmetric (A@A^T + diag, bitwise), so each wave streams
// only the lower triangle (incl. diagonal) of its 128x128 tile:
//   mu[b,u] = sum_{q<r} L_rq (Q_r phi_q + Q_q phi_r) + sum_r L_rr Q_r phi_r
//   sf[b,u] = 1 + 2*sum_{q<r} L_rq phi_r phi_q + sum_r L_rr phi_r^2
// Tasks are float4 chunks of rows; a per-block LDS table maps linear task id
// tau -> byte offset (r*512 + c*16). 2112 tasks = 33 iters/wave, all lanes
// always active.
// ---------------------------------------------------------------------------
__global__ __launch_bounds__(512) void fused_kernel(
    const float* __restrict__ x,
    const float* __restrict__ Q,
    const float* __restrict__ L,
    const float* __restrict__ W1, const float* __restrict__ b1,
    const float* __restrict__ W2, const float* __restrict__ b2,
    const float* __restrict__ W3, const float* __restrict__ b3,
    const float* __restrict__ W4, const float* __restrict__ b4,
    const float* __restrict__ logSigEps,
    float* __restrict__ mu_out,   // 8192 = (B,U,1)
    float* __restrict__ sig_out)  // 65536 = (B,U,U)
{
    const int b = blockIdx.x;
    const int t = threadIdx.x;     // 0..511

    __shared__ float sx[X_DIM];
    __shared__ float h[HID];
    __shared__ alignas(16) float s_phi[PHI];
    __shared__ alignas(16) float s_Q[U_DIM * PHI];   // 4KB
    __shared__ unsigned int s_off[NTASK];            // 8.25KB: tau -> byte offset

    // preload Q (1024 floats) with all 512 threads, and x with the first 32
    {
        const float2* Qg = (const float2*)(Q + (size_t)b * (U_DIM * PHI));
        ((float2*)s_Q)[t] = Qg[t];
    }
    if (t < X_DIM) sx[t] = x[b * X_DIM + t];

    // build the tau -> (r,c) offset table (identical for every block, cheap)
    for (int tau = t; tau < NTASK; tau += 512) {
        int a = (int)((sqrtf(2.0f * (float)tau + 1.0f) - 1.0f) * 0.5f);
        while (2 * (a + 1) * (a + 2) <= tau) ++a;
        while (2 * a * (a + 1) > tau) --a;
        const int o = tau - 2 * a * (a + 1);
        const int d = a + 1;
        const int j = (o >= 2 * d) ? ((o >= 3 * d) ? 3 : 2) : ((o >= d) ? 1 : 0);
        const int c = o - j * d;
        const int r = 4 * a + j;
        s_off[tau] = (unsigned)((r << 9) | (c << 4));  // r*512 + c*16 bytes
    }
    __syncthreads();

    // ---- Phase 1: MLP on threads 0..127 ----
    float acc;
    if (t < HID) {
        acc = b1[t];
#pragma unroll
        for (int k = 0; k < X_DIM; ++k) acc += sx[k] * W1[k * HID + t];
        h[t] = fast_tanh(acc);
    }
    __syncthreads();
    if (t < HID) {
        acc = b2[t];
#pragma unroll 8
        for (int k = 0; k < HID; ++k) acc += h[k] * W2[k * HID + t];
        acc = fast_tanh(acc);
    }
    __syncthreads();
    if (t < HID) h[t] = acc;
    __syncthreads();
    if (t < HID) {
        acc = b3[t];
#pragma unroll 8
        for (int k = 0; k < HID; ++k) acc += h[k] * W3[k * HID + t];
        acc = fast_tanh(acc);
    }
    __syncthreads();
    if (t < HID) h[t] = acc;
    __syncthreads();
    if (t < HID) {
        acc = b4[t];
#pragma unroll 8
        for (int k = 0; k < HID; ++k) acc += h[k] * W4[k * HID + t];
        s_phi[t] = acc;
    }
    __syncthreads();

    // ---- Phase 2: per-wave lower-triangle stream ----
    const int u = t >> 6;          // wave id = u, 0..7
    const int l = t & 63;          // lane

    const char* __restrict__ Lbase =
        (const char*)(L + ((size_t)(b * U_DIM + u)) * (PHI * PHI));
    const float* __restrict__ Qu = s_Q + u * PHI;
    const f4* __restrict__ s_phi4 = (const f4*)s_phi;
    const f4* __restrict__ Qu4 = (const f4*)Qu;

    float accm = 0.0f, accf = 0.0f;
    int tau = l;
#pragma unroll 3
    for (int i = 0; i < 33; ++i, tau += 64) {
        const int off = (int)s_off[tau];
        const f4 v = __builtin_nontemporal_load((const f4*)(Lbase + off));
        const int r = off >> 9;
        const int c = (off >> 4) & 31;
        const float phir = s_phi[r];
        const float Qr   = Qu[r];
        const f4 ph = s_phi4[c];
        const f4 Qv = Qu4[c];
        const int e = 4 * c - r;   // q - r = e + k

        // k = 0..3, weight: q<r -> 1, q==r -> 0.5, q>r -> 0 (padding)
        {
            const float w = (e + 0 < 0) ? 1.0f : ((e + 0 == 0) ? 0.5f : 0.0f);
            const float tv = w * v.x;
            accm += tv * (Qr * ph.x + Qv.x * phir);
            accf += tv * (phir * ph.x);
        }
        {
            const float w = (e + 1 < 0) ? 1.0f : ((e + 1 == 0) ? 0.5f : 0.0f);
            const float tv = w * v.y;
            accm += tv * (Qr * ph.y + Qv.y * phir);
            accf += tv * (phir * ph.y);
        }
        {
            const float w = (e + 2 < 0) ? 1.0f : ((e + 2 == 0) ? 0.5f : 0.0f);
            const float tv = w * v.z;
            accm += tv * (Qr * ph.z + Qv.z * phir);
            accf += tv * (phir * ph.z);
        }
        {
            const float w = (e + 3 < 0) ? 1.0f : ((e + 3 == 0) ? 0.5f : 0.0f);
            const float tv = w * v.w;
            accm += tv * (Qr * ph.w + Qv.w * phir);
            accf += tv * (phir * ph.w);
        }
    }

    // intra-wave butterfly reduction (64 lanes)
#pragma unroll
    for (int off = 1; off < 64; off <<= 1) {
        accm += __shfl_xor(accm, off);
        accf += __shfl_xor(accf, off);
    }

    const int bu = b * U_DIM + u;
    if (l == 0) mu_out[bu] = accm;
    if (l < U_DIM) {
        const float sf = 1.0f + 2.0f * accf;
        sig_out[(size_t)bu * U_DIM + l] = (l == u) ? __expf(logSigEps[u]) * sf : 0.0f;
    }
}

extern "C" void kernel_launch(void* const* d_in, const int* in_sizes, int n_in,
                              void* d_out, int out_size, void* d_ws, size_t ws_size,
                              hipStream_t stream)
{
    const float* x         = (const float*)d_in[0];
    const float* Q         = (const float*)d_in[1];
    const float* L         = (const float*)d_in[2];
    const float* W1        = (const float*)d_in[3];
    const float* b1        = (const float*)d_in[4];
    const float* W2        = (const float*)d_in[5];
    const float* b2        = (const float*)d_in[6];
    const float* W3        = (const float*)d_in[7];
    const float* b3        = (const float*)d_in[8];
    const float* W4        = (const float*)d_in[9];
    const float* b4        = (const float*)d_in[10];
    const float* logSigEps = (const float*)d_in[11];

    float* out     = (float*)d_out;
    float* mu_out  = out;                   // 8192
    float* sig_out = out + BATCH * U_DIM;   // 65536

    fused_kernel<<<BATCH, 512, 0, stream>>>(x, Q, L,
                                            W1, b1, W2, b2, W3, b3, W4, b4,
                                            logSigEps, mu_out, sig_out);
}